// Round 7
// baseline (279.235 us; speedup 1.0000x reference)
//
#include <hip/hip_runtime.h>
#include <stdint.h>

#define D   64
#define L   50
#define NUM_U 30000
#define NUM_I 20000

// r3: float tensors are f32. r4: __shfl(=ds_bpermute) latency-bound. r5:
// readlane->SGPR broadcasts (VALU). r6: H=feat@W precompute in ws, attn on
// projected bf16 mailboxes: 277us, VALUBusy 82%, MfmaUtil 0. r7: Wg projection
// ([hl|hs](4x128) @ Wg(128x64) per block) moved to mfma_f32_16x16x32_bf16.

typedef __attribute__((ext_vector_type(8))) short short8x;   // 8 bf16 (4 VGPR)
typedef __attribute__((ext_vector_type(4))) float f32x4;     // MFMA acc

__device__ __forceinline__ float lof(unsigned int u) {
    union { unsigned int i; float f; } v; v.i = u << 16; return v.f;
}
__device__ __forceinline__ float hif(unsigned int u) {
    union { unsigned int i; float f; } v; v.i = u & 0xffff0000u; return v.f;
}
__device__ __forceinline__ unsigned int f2bfbits(float f) {
    union { float f; unsigned int i; } v; v.f = f;
    return (v.i + 0x7fffu + ((v.i >> 16) & 1u)) >> 16;   // RNE
}
__device__ __forceinline__ unsigned int packbf(float a, float b) {
    return f2bfbits(a) | (f2bfbits(b) << 16);
}
__device__ __forceinline__ float rl(float v, int l) {
    return __int_as_float(__builtin_amdgcn_readlane(__float_as_int(v), l));
}
__device__ __forceinline__ int rli(int v, int l) {
    return __builtin_amdgcn_readlane(v, l);
}

// ---------------- K1: H = feat @ W, packed bf16 pairs (32 dw/row) ----------
__global__ __launch_bounds__(256) void gemm_h(
    const float* __restrict__ user_feat,
    const float* __restrict__ item_feat,
    const float* __restrict__ W_u,
    const float* __restrict__ W_i,
    unsigned int* __restrict__ H)
{
    const int tid = threadIdx.x, lane = tid & 63, wid = tid >> 6;
    int r0 = blockIdx.x * 16 + wid * 4;           // 30000%16==0: no side straddle
    const float* src; const float* W;
    if (r0 < NUM_U) { src = user_feat + (size_t)r0 * D;            W = W_u; }
    else            { src = item_feat + (size_t)(r0 - NUM_U) * D;  W = W_i; }

    float f0 = src[0 * D + lane], f1 = src[1 * D + lane];
    float f2 = src[2 * D + lane], f3 = src[3 * D + lane];
    float a0 = 0.f, a1 = 0.f, a2 = 0.f, a3 = 0.f;
#pragma unroll
    for (int k = 0; k < 64; k++) {
        float wk = W[k * 64 + lane];
        a0 += rl(f0, k) * wk; a1 += rl(f1, k) * wk;
        a2 += rl(f2, k) * wk; a3 += rl(f3, k) * wk;
    }
    int li = (lane & 31) << 1;
    float p0 = __shfl(a0, li), q0 = __shfl(a0, li | 1);
    float p1 = __shfl(a1, li), q1 = __shfl(a1, li | 1);
    float p2 = __shfl(a2, li), q2 = __shfl(a2, li | 1);
    float p3 = __shfl(a3, li), q3 = __shfl(a3, li | 1);
    if (lane < 32) {
        H[(size_t)(r0 + 0) * 32 + lane] = packbf(p0, q0);
        H[(size_t)(r0 + 1) * 32 + lane] = packbf(p1, q1);
        H[(size_t)(r0 + 2) * 32 + lane] = packbf(p2, q2);
        H[(size_t)(r0 + 3) * 32 + lane] = packbf(p3, q3);
    }
}

// ---------------- K2: attention on projected mailboxes (one wave/node) ------
//   e_l = mbh_l.dh + teh[re_o_l] ; e1_l = mbh_last.mbh_l
//   h_long = sum a (mbh_l + tek[re_o_l]) ; h_short = sum a1 mbh_l
//   out = elu([h_long|h_short] @ Wg + f_dst)   <-- MFMA, block-cooperative
__global__ __launch_bounds__(256) void attn_split(
    const unsigned int* __restrict__ H,
    int src_base, int dst_base,
    const float* __restrict__ dst_feat,
    const float* __restrict__ Wg,         // [128,64] f32
    const float* __restrict__ te,         // [50,64] f32
    const float* __restrict__ tek,        // [50,64] f32
    const int* __restrict__ nbr,          // [N,50]
    const int* __restrict__ timev,        // [N,50]
    float* __restrict__ out)              // [N,64]
{
    __shared__ unsigned int te32[L * 33];        // packed bf16, stride 33 dw
    __shared__ unsigned int mbs[4][L * 33];
    __shared__ unsigned short cat16[4 * 136];    // [hl|hs] bf16, stride 136
                                                 // (rows land in distinct banks)

    const int tid = threadIdx.x, lane = tid & 63, wid = tid >> 6;
    const int n = blockIdx.x * 4 + wid;
    const int q4 = lane >> 4, c16 = lane & 15, nb = wid * 16;

    // ---- B-fragments of Wg for this wave's 16-col N-tile (one-time, L1) ----
    // B layout (m89-verified): b[i] = Wg[k = t*32 + q4*8 + i][nb + c16]
    short8x bfr[4];
#pragma unroll
    for (int tK = 0; tK < 4; tK++) {
#pragma unroll
        for (int i = 0; i < 8; i++) {
            float w = Wg[(tK * 32 + q4 * 8 + i) * 64 + nb + c16];
            bfr[tK][i] = (short)f2bfbits(w);
        }
    }

    {   // stage te packed
        const float2* Te2 = (const float2*)te;
        for (int p = tid; p < 1600; p += 256) {
            float2 t2 = Te2[p];
            te32[(p >> 5) * 33 + (p & 31)] = packbf(t2.x, t2.y);
        }
    }
    __syncthreads();

    // ---- neighborhood metadata ----
    int t  = (lane < L) ? timev[(size_t)n * L + lane] : 0;
    int nbv = (lane < L) ? nbr[(size_t)n * L + lane]  : 0;
    unsigned int key  = (lane < L) ? ((((unsigned)t) << 6) | (unsigned)lane) : 0u;
    unsigned int key2 = (lane < L) ? ((((unsigned)t) << 6) | (unsigned)(63 - lane)) : 0u;

    int rank = 0;                       // stable ascending rank = argsort(argsort)
#pragma unroll
    for (int j = 0; j < L; j++) {
        unsigned int kj = (unsigned int)rli((int)key, j);
        rank += (kj < key) ? 1 : 0;
    }
    int re_o = (lane < L) ? (L - 1 - rank) : 0;

    unsigned int m2 = key2;             // first argmax(time)
#pragma unroll
    for (int s = 32; s; s >>= 1) { unsigned int o2 = __shfl_xor(m2, s); m2 = (o2 > m2) ? o2 : m2; }
    const int last = 63 - (int)(m2 & 63u);
    const int rr = (lane < L) ? lane : (L - 1);

    // ---- dh = projected dst row (lanes = d), from packed H ----
    unsigned int ud = H[(size_t)(dst_base + n) * 32 + (lane >> 1)];
    float dh = (lane & 1) ? hif(ud) : lof(ud);

    // ---- gather projected mailbox rows (2 rows/iter, half-wave each) ----
    unsigned int* mbw = mbs[wid];
    {
        const unsigned int* Hs = H + (size_t)src_base * 32;
        int half = lane >> 5, col = lane & 31;
#pragma unroll
        for (int l = 0; l < L; l += 2) {
            int ra = rli(nbv, l), rb = rli(nbv, l + 1);
            int r = half ? rb : ra;
            mbw[(l + half) * 33 + col] = Hs[(size_t)r * 32 + col];
        }
    }
    __syncthreads();

    // ---- mbh_last (lanes = d) ----
    unsigned int ulm = mbw[last * 33 + (lane >> 1)];
    float lm = (lane & 1) ? hif(ulm) : lof(ulm);

    // ---- teh[r] = te[r].dh (lanes = rank) ----
    float teh;
    {
        float b0 = 0.f, b1 = 0.f, b2 = 0.f, b3 = 0.f;
#pragma unroll
        for (int j = 0; j < 32; j += 2) {
            unsigned int u0 = te32[rr * 33 + j];
            unsigned int u1 = te32[rr * 33 + j + 1];
            b0 += lof(u0) * rl(dh, 2 * j + 0);
            b1 += hif(u0) * rl(dh, 2 * j + 1);
            b2 += lof(u1) * rl(dh, 2 * j + 2);
            b3 += hif(u1) * rl(dh, 2 * j + 3);
        }
        teh = (b0 + b1) + (b2 + b3);
    }

    // ---- scores e, e1 (lanes = neighbor) ----
    float e, e1;
    {
        float ea = 0.f, eb = 0.f, qa = 0.f, qb = 0.f;
#pragma unroll
        for (int j = 0; j < 32; j += 2) {
            unsigned int u0 = mbw[rr * 33 + j];
            unsigned int u1 = mbw[rr * 33 + j + 1];
            float m0 = lof(u0), m1 = hif(u0), m2f = lof(u1), m3 = hif(u1);
            ea += m0 * rl(dh, 2 * j + 0) + m1 * rl(dh, 2 * j + 1);
            eb += m2f * rl(dh, 2 * j + 2) + m3 * rl(dh, 2 * j + 3);
            qa += m0 * rl(lm, 2 * j + 0) + m1 * rl(lm, 2 * j + 1);
            qb += m2f * rl(lm, 2 * j + 2) + m3 * rl(lm, 2 * j + 3);
        }
        e = ea + eb; e1 = qa + qb;
    }
    e = (e + __shfl(teh, re_o)) * 0.125f;   // per-lane index: single bpermute
    e1 *= 0.125f;
    if (lane >= L) { e = -3e38f; e1 = -3e38f; }

    // ---- dual softmax over neighbors ----
    float mx = e;
#pragma unroll
    for (int s = 32; s; s >>= 1) { float o2 = __shfl_xor(mx, s); mx = (o2 > mx) ? o2 : mx; }
    float ex = __expf(e - mx);
    float sm = ex;
#pragma unroll
    for (int s = 32; s; s >>= 1) sm += __shfl_xor(sm, s);
    float alpha = ex / sm;

    float mx1 = e1;
#pragma unroll
    for (int s = 32; s; s >>= 1) { float o2 = __shfl_xor(mx1, s); mx1 = (o2 > mx1) ? o2 : mx1; }
    float ex1 = __expf(e1 - mx1);
    float sm1 = ex1;
#pragma unroll
    for (int s = 32; s; s >>= 1) sm1 += __shfl_xor(sm1, s);
    float aw = ex1 / sm1;

    // ---- weighted sums (lanes = d); tek f32 global (coalesced, L1) ----
    float hl, hs;
    {
        float sA = 0.f, sB = 0.f, hA = 0.f, hB = 0.f, tA = 0.f, tB = 0.f;
        int hcol = lane >> 1, odd = lane & 1;
#pragma unroll
        for (int l = 0; l < L; l += 2) {
            float saA = rl(alpha, l),     s1A = rl(aw, l);
            float saB = rl(alpha, l + 1), s1B = rl(aw, l + 1);
            int   roA = rli(re_o, l),     roB = rli(re_o, l + 1);
            unsigned int uA = mbw[(l + 0) * 33 + hcol];
            unsigned int uB = mbw[(l + 1) * 33 + hcol];
            float mA = odd ? hif(uA) : lof(uA);
            float mB = odd ? hif(uB) : lof(uB);
            sA += saA * mA; hA += s1A * mA; tA += saA * tek[roA * 64 + lane];
            sB += saB * mB; hB += s1B * mB; tB += saB * tek[roB * 64 + lane];
        }
        hl = (sA + sB) + (tA + tB);   // h_long (src projection already applied)
        hs = hA + hB;                 // h_short
    }

    // ---- cat = [hl|hs] as bf16 into LDS, one barrier, then MFMA ----
    cat16[wid * 136 + lane]      = (unsigned short)f2bfbits(hl);
    cat16[wid * 136 + 64 + lane] = (unsigned short)f2bfbits(hs);
    __syncthreads();

    // A layout (m89-verified): a[i] = cat[row = lane&3 (dup mod 4)][k = t*32+q4*8+i]
    // D layout: col = lane&15, row = q*4+reg; row==node (mod 4) -> reg q4 = node q4.
    f32x4 acc = {0.f, 0.f, 0.f, 0.f};
#pragma unroll
    for (int tK = 0; tK < 4; tK++) {
        short8x a = *(const short8x*)(cat16 + (lane & 3) * 136 + tK * 32 + q4 * 8);
        acc = __builtin_amdgcn_mfma_f32_16x16x32_bf16(a, bfr[tK], acc, 0, 0, 0);
    }
    float r01 = (q4 & 1) ? acc[1] : acc[0];
    float r23 = (q4 & 1) ? acc[3] : acc[2];
    float pv  = (q4 & 2) ? r23 : r01;            // node q4's value, col nb+c16

    int node = blockIdx.x * 4 + q4;
    float fres = dst_feat[(size_t)node * D + nb + c16];
    float oo = pv + fres;
    oo = (oo > 0.f) ? oo : (__expf(oo) - 1.f);
    out[(size_t)node * D + nb + c16] = oo;
}

// ---------------- fallback: round-5 monolith (passed, 447us) ---------------
__global__ __launch_bounds__(256) void attn_mono(
    const float* __restrict__ src_feat, const float* __restrict__ dst_feat,
    const float* __restrict__ W_src, const float* __restrict__ W_dst,
    const float* __restrict__ Wg, const float* __restrict__ te,
    const float* __restrict__ tek, const int* __restrict__ nbr,
    const int* __restrict__ timev, float* __restrict__ out)
{
    __shared__ unsigned int ws32[64 * 33];
    __shared__ unsigned int te32[L * 33];
    __shared__ unsigned int mbs[4][L * 33];
    const int tid = threadIdx.x, lane = tid & 63, wid = tid >> 6;
    const int n = blockIdx.x * 4 + wid;
    {
        const float2* Wf2 = (const float2*)W_src;
        const float2* Te2 = (const float2*)te;
        for (int idx = tid; idx < 2048; idx += 256) {
            float2 w = Wf2[idx];
            ws32[(idx >> 5) * 33 + (idx & 31)] = packbf(w.x, w.y);
            if (idx < 1600) {
                float2 t2 = Te2[idx];
                te32[(idx >> 5) * 33 + (idx & 31)] = packbf(t2.x, t2.y);
            }
        }
    }
    __syncthreads();
    int t  = (lane < L) ? timev[(size_t)n * L + lane] : 0;
    int nb = (lane < L) ? nbr[(size_t)n * L + lane]  : 0;
    unsigned int key  = (lane < L) ? ((((unsigned)t) << 6) | (unsigned)lane) : 0u;
    unsigned int key2 = (lane < L) ? ((((unsigned)t) << 6) | (unsigned)(63 - lane)) : 0u;
    int rank = 0;
#pragma unroll
    for (int j = 0; j < L; j++) {
        unsigned int kj = (unsigned int)rli((int)key, j);
        rank += (kj < key) ? 1 : 0;
    }
    int re_o = (lane < L) ? (L - 1 - rank) : 0;
    unsigned int m2 = key2;
#pragma unroll
    for (int s = 32; s; s >>= 1) { unsigned int o2 = __shfl_xor(m2, s); m2 = (o2 > m2) ? o2 : m2; }
    const int last = 63 - (int)(m2 & 63u);
    const int rr = (lane < L) ? lane : (L - 1);
    float f = dst_feat[(size_t)n * D + lane];
    float dh;
    {
        float b0 = 0.f, b1 = 0.f, b2 = 0.f, b3 = 0.f;
#pragma unroll
        for (int k = 0; k < 64; k += 4) {
            b0 += rl(f, k + 0) * W_dst[(k + 0) * 64 + lane];
            b1 += rl(f, k + 1) * W_dst[(k + 1) * 64 + lane];
            b2 += rl(f, k + 2) * W_dst[(k + 2) * 64 + lane];
            b3 += rl(f, k + 3) * W_dst[(k + 3) * 64 + lane];
        }
        dh = (b0 + b1) + (b2 + b3);
    }
    float v1;
    {
        float b0 = 0.f, b1 = 0.f, b2 = 0.f, b3 = 0.f;
#pragma unroll
        for (int j = 0; j < 32; j += 2) {
            unsigned int u0 = ws32[lane * 33 + j];
            unsigned int u1 = ws32[lane * 33 + j + 1];
            b0 += lof(u0) * rl(dh, 2 * j + 0);
            b1 += hif(u0) * rl(dh, 2 * j + 1);
            b2 += lof(u1) * rl(dh, 2 * j + 2);
            b3 += hif(u1) * rl(dh, 2 * j + 3);
        }
        v1 = (b0 + b1) + (b2 + b3);
    }
    unsigned int* mbw = mbs[wid];
    {
        const float2* src2 = (const float2*)src_feat;
        int half = lane >> 5, col = lane & 31;
#pragma unroll
        for (int l = 0; l < L; l += 2) {
            int ra = rli(nb, l), rb = rli(nb, l + 1);
            int r = half ? rb : ra;
            float2 v = src2[(size_t)r * 32 + col];
            mbw[(l + half) * 33 + col] = packbf(v.x, v.y);
        }
    }
    __syncthreads();
    unsigned int ul = mbw[last * 33 + (lane >> 1)];
    float rlast = (lane & 1) ? hif(ul) : lof(ul);
    float g;
    {
        float b0 = 0.f, b1 = 0.f, b2 = 0.f, b3 = 0.f;
#pragma unroll
        for (int k = 0; k < 64; k += 4) {
            b0 += rl(rlast, k + 0) * W_src[(k + 0) * 64 + lane];
            b1 += rl(rlast, k + 1) * W_src[(k + 1) * 64 + lane];
            b2 += rl(rlast, k + 2) * W_src[(k + 2) * 64 + lane];
            b3 += rl(rlast, k + 3) * W_src[(k + 3) * 64 + lane];
        }
        g = (b0 + b1) + (b2 + b3);
    }
    float v2;
    {
        float b0 = 0.f, b1 = 0.f, b2 = 0.f, b3 = 0.f;
#pragma unroll
        for (int j = 0; j < 32; j += 2) {
            unsigned int u0 = ws32[lane * 33 + j];
            unsigned int u1 = ws32[lane * 33 + j + 1];
            b0 += lof(u0) * rl(g, 2 * j + 0);
            b1 += hif(u0) * rl(g, 2 * j + 1);
            b2 += lof(u1) * rl(g, 2 * j + 2);
            b3 += hif(u1) * rl(g, 2 * j + 3);
        }
        v2 = (b0 + b1) + (b2 + b3);
    }
    float teh;
    {
        float b0 = 0.f, b1 = 0.f, b2 = 0.f, b3 = 0.f;
#pragma unroll
        for (int j = 0; j < 32; j += 2) {
            unsigned int u0 = te32[rr * 33 + j];
            unsigned int u1 = te32[rr * 33 + j + 1];
            b0 += lof(u0) * rl(dh, 2 * j + 0);
            b1 += hif(u0) * rl(dh, 2 * j + 1);
            b2 += lof(u1) * rl(dh, 2 * j + 2);
            b3 += hif(u1) * rl(dh, 2 * j + 3);
        }
        teh = (b0 + b1) + (b2 + b3);
    }
    float e, e1;
    {
        float ea = 0.f, eb = 0.f, qa = 0.f, qb = 0.f;
#pragma unroll
        for (int j = 0; j < 32; j += 2) {
            unsigned int u0 = mbw[rr * 33 + j];
            unsigned int u1 = mbw[rr * 33 + j + 1];
            float m0 = lof(u0), m1 = hif(u0), m2f = lof(u1), m3 = hif(u1);
            ea += m0 * rl(v1, 2 * j + 0) + m1 * rl(v1, 2 * j + 1);
            eb += m2f * rl(v1, 2 * j + 2) + m3 * rl(v1, 2 * j + 3);
            qa += m0 * rl(v2, 2 * j + 0) + m1 * rl(v2, 2 * j + 1);
            qb += m2f * rl(v2, 2 * j + 2) + m3 * rl(v2, 2 * j + 3);
        }
        e = ea + eb; e1 = qa + qb;
    }
    e = (e + __shfl(teh, re_o)) * 0.125f;
    e1 *= 0.125f;
    if (lane >= L) { e = -3e38f; e1 = -3e38f; }
    float mx = e;
#pragma unroll
    for (int s = 32; s; s >>= 1) { float o2 = __shfl_xor(mx, s); mx = (o2 > mx) ? o2 : mx; }
    float ex = __expf(e - mx);
    float sm = ex;
#pragma unroll
    for (int s = 32; s; s >>= 1) sm += __shfl_xor(sm, s);
    float alpha = ex / sm;
    float mx1 = e1;
#pragma unroll
    for (int s = 32; s; s >>= 1) { float o2 = __shfl_xor(mx1, s); mx1 = (o2 > mx1) ? o2 : mx1; }
    float ex1 = __expf(e1 - mx1);
    float sm1 = ex1;
#pragma unroll
    for (int s = 32; s; s >>= 1) sm1 += __shfl_xor(sm1, s);
    float aw = ex1 / sm1;
    float sl, ss, tacc;
    {
        float sA = 0.f, sB = 0.f, hA = 0.f, hB = 0.f, tA = 0.f, tB = 0.f;
        int hcol = lane >> 1, odd = lane & 1;
#pragma unroll
        for (int l = 0; l < L; l += 2) {
            float saA = rl(alpha, l),     s1A = rl(aw, l);
            float saB = rl(alpha, l + 1), s1B = rl(aw, l + 1);
            int   roA = rli(re_o, l),     roB = rli(re_o, l + 1);
            unsigned int uA = mbw[(l + 0) * 33 + hcol];
            unsigned int uB = mbw[(l + 1) * 33 + hcol];
            float mA = odd ? hif(uA) : lof(uA);
            float mB = odd ? hif(uB) : lof(uB);
            sA += saA * mA; hA += s1A * mA; tA += saA * tek[roA * 64 + lane];
            sB += saB * mB; hB += s1B * mB; tB += saB * tek[roB * 64 + lane];
        }
        sl = sA + sB; ss = hA + hB; tacc = tA + tB;
    }
    float hl, hs;
    {
        float lA = 0.f, lB = 0.f, sA = 0.f, sB = 0.f;
#pragma unroll
        for (int k = 0; k < 64; k += 2) {
            float w0 = W_src[(k + 0) * 64 + lane];
            float w1 = W_src[(k + 1) * 64 + lane];
            lA += rl(sl, k + 0) * w0; sA += rl(ss, k + 0) * w0;
            lB += rl(sl, k + 1) * w1; sB += rl(ss, k + 1) * w1;
        }
        hl = tacc + lA + lB; hs = sA + sB;
    }
    float o;
    {
        float o0 = 0.f, o1 = 0.f, o2 = 0.f, o3 = 0.f;
#pragma unroll
        for (int k = 0; k < 64; k += 2) {
            o0 += rl(hl, k + 0) * Wg[(k + 0) * 64 + lane];
            o1 += rl(hl, k + 1) * Wg[(k + 1) * 64 + lane];
            o2 += rl(hs, k + 0) * Wg[(k + 64) * 64 + lane];
            o3 += rl(hs, k + 1) * Wg[(k + 65) * 64 + lane];
        }
        o = f + (o0 + o1) + (o2 + o3);
    }
    o = (o > 0.f) ? o : (__expf(o) - 1.f);
    out[(size_t)n * D + lane] = o;
}

extern "C" void kernel_launch(void* const* d_in, const int* in_sizes, int n_in,
                              void* d_out, int out_size, void* d_ws, size_t ws_size,
                              hipStream_t stream) {
    const float* user_feat = (const float*)d_in[0];
    const float* item_feat = (const float*)d_in[1];
    const float* W_u  = (const float*)d_in[2];
    const float* W_i  = (const float*)d_in[3];
    const float* Wg_u = (const float*)d_in[4];
    const float* Wg_i = (const float*)d_in[5];
    const float* i_te   = (const float*)d_in[6];
    const float* i_te_k = (const float*)d_in[7];
    const float* u_te   = (const float*)d_in[8];
    const float* u_te_k = (const float*)d_in[9];
    const int* item_nbr  = (const int*)d_in[10];
    const int* item_time = (const int*)d_in[11];
    const int* user_nbr  = (const int*)d_in[12];
    const int* user_time = (const int*)d_in[13];
    (void)in_sizes; (void)n_in; (void)out_size;

    float* outp = (float*)d_out;   // user_out then item_out
    const size_t H_BYTES = (size_t)(NUM_U + NUM_I) * 32 * 4;   // 6.4 MB

    if (ws_size >= H_BYTES) {
        unsigned int* H = (unsigned int*)d_ws;   // packed bf16, users then items
        gemm_h<<<(NUM_U + NUM_I) / 16, 256, 0, stream>>>(
            user_feat, item_feat, W_u, W_i, H);
        attn_split<<<NUM_I / 4, 256, 0, stream>>>(
            H, 0, NUM_U, item_feat, Wg_i, i_te, i_te_k,
            item_nbr, item_time, outp + (size_t)NUM_U * D);
        attn_split<<<NUM_U / 4, 256, 0, stream>>>(
            H, NUM_U, 0, user_feat, Wg_u, u_te, u_te_k,
            user_nbr, user_time, outp);
    } else {
        attn_mono<<<NUM_I / 4, 256, 0, stream>>>(
            user_feat, item_feat, W_u, W_i, Wg_i, i_te, i_te_k,
            item_nbr, item_time, outp + (size_t)NUM_U * D);
        attn_mono<<<NUM_U / 4, 256, 0, stream>>>(
            item_feat, user_feat, W_i, W_u, Wg_u, u_te, u_te_k,
            user_nbr, user_time, outp);
    }
}

// Round 8
// 244.962 us; speedup vs baseline: 1.1399x; 1.1399x over previous
//
#include <hip/hip_runtime.h>
#include <stdint.h>

#define D   64
#define L   50
#define NUM_U 30000
#define NUM_I 20000

// r3: floats are f32. r4: __shfl(ds_bpermute) latency-bound. r5: readlane->SGPR.
// r6: H=feat@W in ws (packed bf16): 277us, VALU-issue-bound. r7: Wg-MFMA epilogue
// NEUTRAL but hardware-verified A/B/D fragment layouts. r8: scores+teh+sums+tek
// all on MFMA; te staging + early barriers removed; WgT/teT/tekT bf16-packed in ws.

typedef __attribute__((ext_vector_type(8))) short short8x;   // 8 bf16
typedef __attribute__((ext_vector_type(4))) float f32x4;     // MFMA acc

__device__ __forceinline__ float lof(unsigned int u) {
    union { unsigned int i; float f; } v; v.i = u << 16; return v.f;
}
__device__ __forceinline__ float hif(unsigned int u) {
    union { unsigned int i; float f; } v; v.i = u & 0xffff0000u; return v.f;
}
__device__ __forceinline__ unsigned int f2bfbits(float f) {
    union { float f; unsigned int i; } v; v.f = f;
    return (v.i + 0x7fffu + ((v.i >> 16) & 1u)) >> 16;   // RNE
}
__device__ __forceinline__ unsigned int packbf(float a, float b) {
    return f2bfbits(a) | (f2bfbits(b) << 16);
}
__device__ __forceinline__ float rl(float v, int l) {
    return __int_as_float(__builtin_amdgcn_readlane(__float_as_int(v), l));
}
__device__ __forceinline__ int rli(int v, int l) {
    return __builtin_amdgcn_readlane(v, l);
}

// ---------------- K0: bf16-pack transposed weights into ws ------------------
// WgP[n][k] = Wg[k][n] (64x128), teP[r][k] = te[r][k] rows padded 0 (64x64),
// tekP[d][r] = tek[r][d] padded 0 (64x64).
__global__ void pack_aux(const float* __restrict__ Wg_i, const float* __restrict__ Wg_u,
                         const float* __restrict__ te_i, const float* __restrict__ te_u,
                         const float* __restrict__ tk_i, const float* __restrict__ tk_u,
                         unsigned short* __restrict__ WgPi, unsigned short* __restrict__ WgPu,
                         unsigned short* __restrict__ tePi, unsigned short* __restrict__ tePu,
                         unsigned short* __restrict__ tkPi, unsigned short* __restrict__ tkPu)
{
    int gid = blockIdx.x * 256 + threadIdx.x, gs = gridDim.x * 256;
    for (int idx = gid; idx < 8192; idx += gs) {
        int n = idx >> 7, k = idx & 127;
        WgPi[idx] = (unsigned short)f2bfbits(Wg_i[k * 64 + n]);
        WgPu[idx] = (unsigned short)f2bfbits(Wg_u[k * 64 + n]);
    }
    for (int idx = gid; idx < 4096; idx += gs) {
        int r = idx >> 6, k = idx & 63;
        tePi[idx] = (r < L) ? (unsigned short)f2bfbits(te_i[r * 64 + k]) : 0;
        tePu[idx] = (r < L) ? (unsigned short)f2bfbits(te_u[r * 64 + k]) : 0;
        int d = idx >> 6, rr = idx & 63;
        tkPi[idx] = (rr < L) ? (unsigned short)f2bfbits(tk_i[rr * 64 + d]) : 0;
        tkPu[idx] = (rr < L) ? (unsigned short)f2bfbits(tk_u[rr * 64 + d]) : 0;
    }
}

// ---------------- K1: H = feat @ W, packed bf16 pairs (32 dw/row) ----------
__global__ __launch_bounds__(256) void gemm_h(
    const float* __restrict__ user_feat,
    const float* __restrict__ item_feat,
    const float* __restrict__ W_u,
    const float* __restrict__ W_i,
    unsigned int* __restrict__ H)
{
    const int tid = threadIdx.x, lane = tid & 63, wid = tid >> 6;
    int r0 = blockIdx.x * 16 + wid * 4;
    const float* src; const float* W;
    if (r0 < NUM_U) { src = user_feat + (size_t)r0 * D;            W = W_u; }
    else            { src = item_feat + (size_t)(r0 - NUM_U) * D;  W = W_i; }

    float f0 = src[0 * D + lane], f1 = src[1 * D + lane];
    float f2 = src[2 * D + lane], f3 = src[3 * D + lane];
    float a0 = 0.f, a1 = 0.f, a2 = 0.f, a3 = 0.f;
#pragma unroll
    for (int k = 0; k < 64; k++) {
        float wk = W[k * 64 + lane];
        a0 += rl(f0, k) * wk; a1 += rl(f1, k) * wk;
        a2 += rl(f2, k) * wk; a3 += rl(f3, k) * wk;
    }
    int li = (lane & 31) << 1;
    float p0 = __shfl(a0, li), q0 = __shfl(a0, li | 1);
    float p1 = __shfl(a1, li), q1 = __shfl(a1, li | 1);
    float p2 = __shfl(a2, li), q2 = __shfl(a2, li | 1);
    float p3 = __shfl(a3, li), q3 = __shfl(a3, li | 1);
    if (lane < 32) {
        H[(size_t)(r0 + 0) * 32 + lane] = packbf(p0, q0);
        H[(size_t)(r0 + 1) * 32 + lane] = packbf(p1, q1);
        H[(size_t)(r0 + 2) * 32 + lane] = packbf(p2, q2);
        H[(size_t)(r0 + 3) * 32 + lane] = packbf(p3, q3);
    }
}

// ---------------- K2: attention, MFMA scores+teh+sums+tek -------------------
__global__ __launch_bounds__(256, 4) void attn_ws(
    const unsigned int* __restrict__ H,
    int src_base, int dst_base,
    const float* __restrict__ dst_feat,
    const unsigned short* __restrict__ WgP,   // [64][128]
    const unsigned short* __restrict__ teP,   // [64][64]
    const unsigned short* __restrict__ tekP,  // [64][64]
    const int* __restrict__ nbr,
    const int* __restrict__ timev,
    float* __restrict__ out)
{
    __shared__ unsigned int   mbs[4][56 * 33];   // mailbox rows 0..49 + zero pad 50..55
    __shared__ float          esc[4][192];       // e | e1 | teh redistribution
    __shared__ unsigned short ala[4][192];       // alpha | a1 | beta (bf16)
    __shared__ unsigned short dhlm[4][128];      // dh | lm (bf16)
    __shared__ unsigned short cat16[4][136];     // [hl|hs] per node (stride 272B, 16B-mult)

    const int tid = threadIdx.x, lane = tid & 63, wid = tid >> 6;
    const int n = blockIdx.x * 4 + wid;
    const int q4 = lane >> 4, c16 = lane & 15;

    unsigned int* mbw = mbs[wid];
    unsigned short* mbw_sh = (unsigned short*)mbw;

    // zero pad rows 50..55 (k-clamp target for sums; scores n>=50 masked anyway)
    for (int p = lane; p < 198; p += 64) mbw[1650 + p] = 0;

    // ---- metadata ----
    int t   = (lane < L) ? timev[(size_t)n * L + lane] : 0;
    int nbv = (lane < L) ? nbr[(size_t)n * L + lane]  : 0;
    unsigned int key  = (lane < L) ? ((((unsigned)t) << 6) | (unsigned)lane) : 0u;
    unsigned int key2 = (lane < L) ? ((((unsigned)t) << 6) | (unsigned)(63 - lane)) : 0u;

    int rank = 0;
#pragma unroll
    for (int j = 0; j < L; j++) {
        unsigned int kj = (unsigned int)rli((int)key, j);
        rank += (kj < key) ? 1 : 0;
    }
    // pad lanes get identity slots (distinct beta/teh slots, no write races)
    int re_o = (lane < L) ? (L - 1 - rank) : lane;

    unsigned int m2 = key2;
#pragma unroll
    for (int s = 32; s; s >>= 1) { unsigned int o2 = __shfl_xor(m2, s); m2 = (o2 > m2) ? o2 : m2; }
    const int last = 63 - (int)(m2 & 63u);

    // ---- dh (lanes = d) from packed H ----
    unsigned int ud = H[(size_t)(dst_base + n) * 32 + (lane >> 1)];
    float dh = (lane & 1) ? hif(ud) : lof(ud);
    dhlm[wid][lane] = (unsigned short)f2bfbits(dh);

    // ---- gather mailbox rows (2 rows/iter, half-wave each) ----
    {
        const unsigned int* Hs = H + (size_t)src_base * 32;
        int half = lane >> 5, col = lane & 31;
#pragma unroll
        for (int l = 0; l < L; l += 2) {
            int ra = rli(nbv, l), rb = rli(nbv, l + 1);
            int r = half ? rb : ra;
            mbw[(l + half) * 33 + col] = Hs[(size_t)r * 32 + col];
        }
    }
    // same-wave LDS write->read ordering is guaranteed (lgkmcnt); no barrier.

    unsigned int ulm = mbw[last * 33 + (lane >> 1)];
    float lm = (lane & 1) ? hif(ulm) : lof(ulm);
    dhlm[wid][64 + lane] = (unsigned short)f2bfbits(lm);

    // ---- scores + teh via MFMA: D=[dh;lm]·M^T, D_t=[dh]·te^T ----
    // A[m][k]: row m&1 of dhlm (r7-verified A layout). B[k][n]=M[n][k]: row-read.
    f32x4 zero4 = {0.f, 0.f, 0.f, 0.f};
    f32x4 acc_e[4], acc_t[4];
#pragma unroll
    for (int nt = 0; nt < 4; nt++) { acc_e[nt] = zero4; acc_t[nt] = zero4; }
    {
        const unsigned short* dl = dhlm[wid];
#pragma unroll
        for (int kt = 0; kt < 2; kt++) {
            short8x afr = *(const short8x*)(dl + (c16 & 1) * 64 + kt * 32 + q4 * 8);
#pragma unroll
            for (int nt = 0; nt < 4; nt++) {
                int row = c16 + 16 * nt;
                union { short8x v; unsigned int u[4]; } bu;
                int base = row * 33 + kt * 16 + q4 * 4;
                bu.u[0] = mbw[base + 0]; bu.u[1] = mbw[base + 1];
                bu.u[2] = mbw[base + 2]; bu.u[3] = mbw[base + 3];
                acc_e[nt] = __builtin_amdgcn_mfma_f32_16x16x32_bf16(afr, bu.v, acc_e[nt], 0, 0, 0);
                short8x bt = *(const short8x*)(teP + row * 64 + kt * 32 + q4 * 8);
                acc_t[nt] = __builtin_amdgcn_mfma_f32_16x16x32_bf16(afr, bt, acc_t[nt], 0, 0, 0);
            }
        }
    }
    // redistribute: rows 0/1 live in quad-0 regs 0/1 (r7-verified D layout)
    if (q4 == 0) {
#pragma unroll
        for (int nt = 0; nt < 4; nt++) {
            esc[wid][c16 + 16 * nt]       = acc_e[nt][0];   // e
            esc[wid][64 + c16 + 16 * nt]  = acc_e[nt][1];   // e1
            esc[wid][128 + c16 + 16 * nt] = acc_t[nt][0];   // teh (rank-indexed)
        }
    }
    float e  = esc[wid][lane];
    float e1 = esc[wid][64 + lane];
    float th = esc[wid][128 + re_o];

    e = (e + th) * 0.125f;
    e1 *= 0.125f;
    if (lane >= L) { e = -3e38f; e1 = -3e38f; }

    // ---- dual softmax over neighbors ----
    float mx = e;
#pragma unroll
    for (int s = 32; s; s >>= 1) { float o2 = __shfl_xor(mx, s); mx = (o2 > mx) ? o2 : mx; }
    float ex = __expf(e - mx);
    float sm = ex;
#pragma unroll
    for (int s = 32; s; s >>= 1) sm += __shfl_xor(sm, s);
    float alpha = ex / sm;

    float mx1 = e1;
#pragma unroll
    for (int s = 32; s; s >>= 1) { float o2 = __shfl_xor(mx1, s); mx1 = (o2 > mx1) ? o2 : mx1; }
    float ex1 = __expf(e1 - mx1);
    float sm1 = ex1;
#pragma unroll
    for (int s = 32; s; s >>= 1) sm1 += __shfl_xor(sm1, s);
    float aw = ex1 / sm1;

    // ---- alpha/a1/beta (bf16). pad lanes have alpha=aw=0 (e=-3e38) ----
    ala[wid][lane]        = (unsigned short)f2bfbits(alpha);
    ala[wid][64 + lane]   = (unsigned short)f2bfbits(aw);
    ala[wid][128 + re_o]  = (unsigned short)f2bfbits(alpha);   // beta[r] = alpha at rank r

    // ---- sums via MFMA: [alpha;a1]·M (col-reads) + [beta]·tek^T (ws, L1) ----
    f32x4 acc_s[4], acc_k[4];
#pragma unroll
    for (int nt = 0; nt < 4; nt++) { acc_s[nt] = zero4; acc_k[nt] = zero4; }
    {
        const unsigned short* alp = ala[wid];
#pragma unroll
        for (int kt = 0; kt < 2; kt++) {
            short8x aS = *(const short8x*)(alp + (c16 & 1) * 64 + kt * 32 + q4 * 8);
            short8x aB = *(const short8x*)(alp + 128 + kt * 32 + q4 * 8);
#pragma unroll
            for (int nt = 0; nt < 4; nt++) {
                int dcol = c16 + 16 * nt;
                short8x bM;
                if (kt == 0) {
                    int b0 = (q4 * 8) * 66 + dcol;
#pragma unroll
                    for (int i = 0; i < 8; i++) bM[i] = (short)mbw_sh[b0 + i * 66];
                } else {
#pragma unroll
                    for (int i = 0; i < 8; i++) {
                        int k = 32 + q4 * 8 + i;
                        int kk = (k < L) ? k : L;          // row 50 is zeroed pad
                        bM[i] = (short)mbw_sh[kk * 66 + dcol];
                    }
                }
                acc_s[nt] = __builtin_amdgcn_mfma_f32_16x16x32_bf16(aS, bM, acc_s[nt], 0, 0, 0);
                short8x bK = *(const short8x*)(tekP + dcol * 64 + kt * 32 + q4 * 8);
                acc_k[nt] = __builtin_amdgcn_mfma_f32_16x16x32_bf16(aB, bK, acc_k[nt], 0, 0, 0);
            }
        }
    }
    // cat = [hl|hs]: hl = alpha-sum + beta·tek, hs = a1-sum (quad-0 regs 0/1)
    if (q4 == 0) {
#pragma unroll
        for (int nt = 0; nt < 4; nt++) {
            cat16[wid][c16 + 16 * nt]      = (unsigned short)f2bfbits(acc_s[nt][0] + acc_k[nt][0]);
            cat16[wid][64 + c16 + 16 * nt] = (unsigned short)f2bfbits(acc_s[nt][1]);
        }
    }
    __syncthreads();   // only barrier: epilogue mixes waves' cat rows

    // ---- epilogue (r7-verified): out = elu(cat @ Wg + f) ----
    short8x bfr[4];
#pragma unroll
    for (int tK = 0; tK < 4; tK++)
        bfr[tK] = *(const short8x*)(WgP + (wid * 16 + c16) * 128 + tK * 32 + q4 * 8);

    f32x4 acc = zero4;
#pragma unroll
    for (int tK = 0; tK < 4; tK++) {
        short8x a = *(const short8x*)(&cat16[lane & 3][tK * 32 + q4 * 8]);
        acc = __builtin_amdgcn_mfma_f32_16x16x32_bf16(a, bfr[tK], acc, 0, 0, 0);
    }
    float r01 = (q4 & 1) ? acc[1] : acc[0];
    float r23 = (q4 & 1) ? acc[3] : acc[2];
    float pv  = (q4 & 2) ? r23 : r01;

    int node = blockIdx.x * 4 + q4;
    float fres = dst_feat[(size_t)node * D + wid * 16 + c16];
    float oo = pv + fres;
    oo = (oo > 0.f) ? oo : (__expf(oo) - 1.f);
    out[(size_t)node * D + wid * 16 + c16] = oo;
}

// ---------------- fallback: round-5 monolith (passed, 447us) ---------------
__global__ __launch_bounds__(256) void attn_mono(
    const float* __restrict__ src_feat, const float* __restrict__ dst_feat,
    const float* __restrict__ W_src, const float* __restrict__ W_dst,
    const float* __restrict__ Wg, const float* __restrict__ te,
    const float* __restrict__ tek, const int* __restrict__ nbr,
    const int* __restrict__ timev, float* __restrict__ out)
{
    __shared__ unsigned int ws32[64 * 33];
    __shared__ unsigned int te32[L * 33];
    __shared__ unsigned int mbs[4][L * 33];
    const int tid = threadIdx.x, lane = tid & 63, wid = tid >> 6;
    const int n = blockIdx.x * 4 + wid;
    {
        const float2* Wf2 = (const float2*)W_src;
        const float2* Te2 = (const float2*)te;
        for (int idx = tid; idx < 2048; idx += 256) {
            float2 w = Wf2[idx];
            ws32[(idx >> 5) * 33 + (idx & 31)] = packbf(w.x, w.y);
            if (idx < 1600) {
                float2 t2 = Te2[idx];
                te32[(idx >> 5) * 33 + (idx & 31)] = packbf(t2.x, t2.y);
            }
        }
    }
    __syncthreads();
    int t  = (lane < L) ? timev[(size_t)n * L + lane] : 0;
    int nb = (lane < L) ? nbr[(size_t)n * L + lane]  : 0;
    unsigned int key  = (lane < L) ? ((((unsigned)t) << 6) | (unsigned)lane) : 0u;
    unsigned int key2 = (lane < L) ? ((((unsigned)t) << 6) | (unsigned)(63 - lane)) : 0u;
    int rank = 0;
#pragma unroll
    for (int j = 0; j < L; j++) {
        unsigned int kj = (unsigned int)rli((int)key, j);
        rank += (kj < key) ? 1 : 0;
    }
    int re_o = (lane < L) ? (L - 1 - rank) : 0;
    unsigned int m2 = key2;
#pragma unroll
    for (int s = 32; s; s >>= 1) { unsigned int o2 = __shfl_xor(m2, s); m2 = (o2 > m2) ? o2 : m2; }
    const int last = 63 - (int)(m2 & 63u);
    const int rr = (lane < L) ? lane : (L - 1);
    float f = dst_feat[(size_t)n * D + lane];
    float dh;
    {
        float b0 = 0.f, b1 = 0.f, b2 = 0.f, b3 = 0.f;
#pragma unroll
        for (int k = 0; k < 64; k += 4) {
            b0 += rl(f, k + 0) * W_dst[(k + 0) * 64 + lane];
            b1 += rl(f, k + 1) * W_dst[(k + 1) * 64 + lane];
            b2 += rl(f, k + 2) * W_dst[(k + 2) * 64 + lane];
            b3 += rl(f, k + 3) * W_dst[(k + 3) * 64 + lane];
        }
        dh = (b0 + b1) + (b2 + b3);
    }
    float v1;
    {
        float b0 = 0.f, b1 = 0.f, b2 = 0.f, b3 = 0.f;
#pragma unroll
        for (int j = 0; j < 32; j += 2) {
            unsigned int u0 = ws32[lane * 33 + j];
            unsigned int u1 = ws32[lane * 33 + j + 1];
            b0 += lof(u0) * rl(dh, 2 * j + 0);
            b1 += hif(u0) * rl(dh, 2 * j + 1);
            b2 += lof(u1) * rl(dh, 2 * j + 2);
            b3 += hif(u1) * rl(dh, 2 * j + 3);
        }
        v1 = (b0 + b1) + (b2 + b3);
    }
    unsigned int* mbw = mbs[wid];
    {
        const float2* src2 = (const float2*)src_feat;
        int half = lane >> 5, col = lane & 31;
#pragma unroll
        for (int l = 0; l < L; l += 2) {
            int ra = rli(nb, l), rb = rli(nb, l + 1);
            int r = half ? rb : ra;
            float2 v = src2[(size_t)r * 32 + col];
            mbw[(l + half) * 33 + col] = packbf(v.x, v.y);
        }
    }
    __syncthreads();
    unsigned int ul = mbw[last * 33 + (lane >> 1)];
    float rlast = (lane & 1) ? hif(ul) : lof(ul);
    float g;
    {
        float b0 = 0.f, b1 = 0.f, b2 = 0.f, b3 = 0.f;
#pragma unroll
        for (int k = 0; k < 64; k += 4) {
            b0 += rl(rlast, k + 0) * W_src[(k + 0) * 64 + lane];
            b1 += rl(rlast, k + 1) * W_src[(k + 1) * 64 + lane];
            b2 += rl(rlast, k + 2) * W_src[(k + 2) * 64 + lane];
            b3 += rl(rlast, k + 3) * W_src[(k + 3) * 64 + lane];
        }
        g = (b0 + b1) + (b2 + b3);
    }
    float v2;
    {
        float b0 = 0.f, b1 = 0.f, b2 = 0.f, b3 = 0.f;
#pragma unroll
        for (int j = 0; j < 32; j += 2) {
            unsigned int u0 = ws32[lane * 33 + j];
            unsigned int u1 = ws32[lane * 33 + j + 1];
            b0 += lof(u0) * rl(g, 2 * j + 0);
            b1 += hif(u0) * rl(g, 2 * j + 1);
            b2 += lof(u1) * rl(g, 2 * j + 2);
            b3 += hif(u1) * rl(g, 2 * j + 3);
        }
        v2 = (b0 + b1) + (b2 + b3);
    }
    float teh;
    {
        float b0 = 0.f, b1 = 0.f, b2 = 0.f, b3 = 0.f;
#pragma unroll
        for (int j = 0; j < 32; j += 2) {
            unsigned int u0 = te32[rr * 33 + j];
            unsigned int u1 = te32[rr * 33 + j + 1];
            b0 += lof(u0) * rl(dh, 2 * j + 0);
            b1 += hif(u0) * rl(dh, 2 * j + 1);
            b2 += lof(u1) * rl(dh, 2 * j + 2);
            b3 += hif(u1) * rl(dh, 2 * j + 3);
        }
        teh = (b0 + b1) + (b2 + b3);
    }
    float e, e1;
    {
        float ea = 0.f, eb = 0.f, qa = 0.f, qb = 0.f;
#pragma unroll
        for (int j = 0; j < 32; j += 2) {
            unsigned int u0 = mbw[rr * 33 + j];
            unsigned int u1 = mbw[rr * 33 + j + 1];
            float m0 = lof(u0), m1 = hif(u0), m2f = lof(u1), m3 = hif(u1);
            ea += m0 * rl(v1, 2 * j + 0) + m1 * rl(v1, 2 * j + 1);
            eb += m2f * rl(v1, 2 * j + 2) + m3 * rl(v1, 2 * j + 3);
            qa += m0 * rl(v2, 2 * j + 0) + m1 * rl(v2, 2 * j + 1);
            qb += m2f * rl(v2, 2 * j + 2) + m3 * rl(v2, 2 * j + 3);
        }
        e = ea + eb; e1 = qa + qb;
    }
    e = (e + __shfl(teh, re_o)) * 0.125f;
    e1 *= 0.125f;
    if (lane >= L) { e = -3e38f; e1 = -3e38f; }
    float mx = e;
#pragma unroll
    for (int s = 32; s; s >>= 1) { float o2 = __shfl_xor(mx, s); mx = (o2 > mx) ? o2 : mx; }
    float ex = __expf(e - mx);
    float sm = ex;
#pragma unroll
    for (int s = 32; s; s >>= 1) sm += __shfl_xor(sm, s);
    float alpha = ex / sm;
    float mx1 = e1;
#pragma unroll
    for (int s = 32; s; s >>= 1) { float o2 = __shfl_xor(mx1, s); mx1 = (o2 > mx1) ? o2 : mx1; }
    float ex1 = __expf(e1 - mx1);
    float sm1 = ex1;
#pragma unroll
    for (int s = 32; s; s >>= 1) sm1 += __shfl_xor(sm1, s);
    float aw = ex1 / sm1;
    float sl, ss, tacc;
    {
        float sA = 0.f, sB = 0.f, hA = 0.f, hB = 0.f, tA = 0.f, tB = 0.f;
        int hcol = lane >> 1, odd = lane & 1;
#pragma unroll
        for (int l = 0; l < L; l += 2) {
            float saA = rl(alpha, l),     s1A = rl(aw, l);
            float saB = rl(alpha, l + 1), s1B = rl(aw, l + 1);
            int   roA = rli(re_o, l),     roB = rli(re_o, l + 1);
            unsigned int uA = mbw[(l + 0) * 33 + hcol];
            unsigned int uB = mbw[(l + 1) * 33 + hcol];
            float mA = odd ? hif(uA) : lof(uA);
            float mB = odd ? hif(uB) : lof(uB);
            sA += saA * mA; hA += s1A * mA; tA += saA * tek[roA * 64 + lane];
            sB += saB * mB; hB += s1B * mB; tB += saB * tek[roB * 64 + lane];
        }
        sl = sA + sB; ss = hA + hB; tacc = tA + tB;
    }
    float hl, hs;
    {
        float lA = 0.f, lB = 0.f, sA = 0.f, sB = 0.f;
#pragma unroll
        for (int k = 0; k < 64; k += 2) {
            float w0 = W_src[(k + 0) * 64 + lane];
            float w1 = W_src[(k + 1) * 64 + lane];
            lA += rl(sl, k + 0) * w0; sA += rl(ss, k + 0) * w0;
            lB += rl(sl, k + 1) * w1; sB += rl(ss, k + 1) * w1;
        }
        hl = tacc + lA + lB; hs = sA + sB;
    }
    float o;
    {
        float o0 = 0.f, o1 = 0.f, o2 = 0.f, o3 = 0.f;
#pragma unroll
        for (int k = 0; k < 64; k += 2) {
            o0 += rl(hl, k + 0) * Wg[(k + 0) * 64 + lane];
            o1 += rl(hl, k + 1) * Wg[(k + 1) * 64 + lane];
            o2 += rl(hs, k + 0) * Wg[(k + 64) * 64 + lane];
            o3 += rl(hs, k + 1) * Wg[(k + 65) * 64 + lane];
        }
        o = f + (o0 + o1) + (o2 + o3);
    }
    o = (o > 0.f) ? o : (__expf(o) - 1.f);
    out[(size_t)n * D + lane] = o;
}

extern "C" void kernel_launch(void* const* d_in, const int* in_sizes, int n_in,
                              void* d_out, int out_size, void* d_ws, size_t ws_size,
                              hipStream_t stream) {
    const float* user_feat = (const float*)d_in[0];
    const float* item_feat = (const float*)d_in[1];
    const float* W_u  = (const float*)d_in[2];
    const float* W_i  = (const float*)d_in[3];
    const float* Wg_u = (const float*)d_in[4];
    const float* Wg_i = (const float*)d_in[5];
    const float* i_te   = (const float*)d_in[6];
    const float* i_te_k = (const float*)d_in[7];
    const float* u_te   = (const float*)d_in[8];
    const float* u_te_k = (const float*)d_in[9];
    const int* item_nbr  = (const int*)d_in[10];
    const int* item_time = (const int*)d_in[11];
    const int* user_nbr  = (const int*)d_in[12];
    const int* user_time = (const int*)d_in[13];
    (void)in_sizes; (void)n_in; (void)out_size;

    float* outp = (float*)d_out;
    const size_t H_BYTES = (size_t)(NUM_U + NUM_I) * 32 * 4;            // 6.4 MB
    const size_t NEED = H_BYTES + 2 * 16384 + 4 * 8192;                 // +64 KB aux

    if (ws_size >= NEED) {
        unsigned int* Hp = (unsigned int*)d_ws;
        unsigned char* aux = (unsigned char*)d_ws + H_BYTES;
        unsigned short* WgPi = (unsigned short*)(aux);
        unsigned short* WgPu = (unsigned short*)(aux + 16384);
        unsigned short* tePi = (unsigned short*)(aux + 32768);
        unsigned short* tePu = (unsigned short*)(aux + 40960);
        unsigned short* tkPi = (unsigned short*)(aux + 49152);
        unsigned short* tkPu = (unsigned short*)(aux + 57344);

        pack_aux<<<16, 256, 0, stream>>>(Wg_i, Wg_u, i_te, u_te, i_te_k, u_te_k,
                                         WgPi, WgPu, tePi, tePu, tkPi, tkPu);
        gemm_h<<<(NUM_U + NUM_I) / 16, 256, 0, stream>>>(
            user_feat, item_feat, W_u, W_i, Hp);
        // item side: mailbox = H user rows, dst = H item rows
        attn_ws<<<NUM_I / 4, 256, 0, stream>>>(
            Hp, 0, NUM_U, item_feat, WgPi, tePi, tkPi,
            item_nbr, item_time, outp + (size_t)NUM_U * D);
        // user side: mailbox = H item rows, dst = H user rows
        attn_ws<<<NUM_U / 4, 256, 0, stream>>>(
            Hp, NUM_U, 0, user_feat, WgPu, tePu, tkPu,
            user_nbr, user_time, outp);
    } else {
        attn_mono<<<NUM_I / 4, 256, 0, stream>>>(
            user_feat, item_feat, W_u, W_i, Wg_i, i_te, i_te_k,
            item_nbr, item_time, outp + (size_t)NUM_U * D);
        attn_mono<<<NUM_U / 4, 256, 0, stream>>>(
            item_feat, user_feat, W_i, W_u, Wg_u, u_te, u_te_k,
            user_nbr, user_time, outp);
    }
}

// Round 9
// 241.539 us; speedup vs baseline: 1.1561x; 1.0142x over previous
//
#include <hip/hip_runtime.h>
#include <stdint.h>

#define D   64
#define L   50
#define NUM_U 30000
#define NUM_I 20000
#define PW  1976   // per-wave LDS dwords: mailbox 1683 (+1 align) | escX 192 | dla 96, rounded to 8

// r3: floats are f32. r4: __shfl(ds_bpermute) latency-bound. r5: readlane->SGPR.
// r6: H precompute in ws. r7: Wg-MFMA epilogue (verified layouts). r8: all bulk
// math on MFMA: 245us, VALU 40% + MFMA 8% -> latency-bound, 4 blocks/CU.
// r9: LDS 36.4->30.9KB (5 blocks/CU), fuse 4 dispatches into 2.

typedef __attribute__((ext_vector_type(8))) short short8x;   // 8 bf16
typedef __attribute__((ext_vector_type(4))) float f32x4;     // MFMA acc

__device__ __forceinline__ float lof(unsigned int u) {
    union { unsigned int i; float f; } v; v.i = u << 16; return v.f;
}
__device__ __forceinline__ float hif(unsigned int u) {
    union { unsigned int i; float f; } v; v.i = u & 0xffff0000u; return v.f;
}
__device__ __forceinline__ unsigned int f2bfbits(float f) {
    union { float f; unsigned int i; } v; v.f = f;
    return (v.i + 0x7fffu + ((v.i >> 16) & 1u)) >> 16;   // RNE
}
__device__ __forceinline__ unsigned int packbf(float a, float b) {
    return f2bfbits(a) | (f2bfbits(b) << 16);
}
__device__ __forceinline__ float rl(float v, int l) {
    return __int_as_float(__builtin_amdgcn_readlane(__float_as_int(v), l));
}
__device__ __forceinline__ int rli(int v, int l) {
    return __builtin_amdgcn_readlane(v, l);
}

// ---------------- K1: fused prep: H = feat@W  +  bf16 weight packing --------
__global__ __launch_bounds__(256) void prep(
    const float* __restrict__ user_feat, const float* __restrict__ item_feat,
    const float* __restrict__ W_u, const float* __restrict__ W_i,
    const float* __restrict__ Wg_i, const float* __restrict__ Wg_u,
    const float* __restrict__ te_i, const float* __restrict__ te_u,
    const float* __restrict__ tk_i, const float* __restrict__ tk_u,
    unsigned int* __restrict__ H,
    unsigned short* __restrict__ WgPi, unsigned short* __restrict__ WgPu,
    unsigned short* __restrict__ tePi, unsigned short* __restrict__ tePu,
    unsigned short* __restrict__ tkPi, unsigned short* __restrict__ tkPu)
{
    const int tid = threadIdx.x;
    if (blockIdx.x < 3125) {
        const int lane = tid & 63, wid = tid >> 6;
        int r0 = blockIdx.x * 16 + wid * 4;           // 30000%16==0: no straddle
        const float* src; const float* W;
        if (r0 < NUM_U) { src = user_feat + (size_t)r0 * D;            W = W_u; }
        else            { src = item_feat + (size_t)(r0 - NUM_U) * D;  W = W_i; }
        float f0 = src[0 * D + lane], f1 = src[1 * D + lane];
        float f2 = src[2 * D + lane], f3 = src[3 * D + lane];
        float a0 = 0.f, a1 = 0.f, a2 = 0.f, a3 = 0.f;
#pragma unroll
        for (int k = 0; k < 64; k++) {
            float wk = W[k * 64 + lane];
            a0 += rl(f0, k) * wk; a1 += rl(f1, k) * wk;
            a2 += rl(f2, k) * wk; a3 += rl(f3, k) * wk;
        }
        int li = (lane & 31) << 1;
        float p0 = __shfl(a0, li), q0 = __shfl(a0, li | 1);
        float p1 = __shfl(a1, li), q1 = __shfl(a1, li | 1);
        float p2 = __shfl(a2, li), q2 = __shfl(a2, li | 1);
        float p3 = __shfl(a3, li), q3 = __shfl(a3, li | 1);
        if (lane < 32) {
            H[(size_t)(r0 + 0) * 32 + lane] = packbf(p0, q0);
            H[(size_t)(r0 + 1) * 32 + lane] = packbf(p1, q1);
            H[(size_t)(r0 + 2) * 32 + lane] = packbf(p2, q2);
            H[(size_t)(r0 + 3) * 32 + lane] = packbf(p3, q3);
        }
    } else {
        int gid = (blockIdx.x - 3125) * 256 + tid;     // 16 blocks, gs=4096
        for (int idx = gid; idx < 8192; idx += 4096) {
            int n = idx >> 7, k = idx & 127;
            WgPi[idx] = (unsigned short)f2bfbits(Wg_i[k * 64 + n]);
            WgPu[idx] = (unsigned short)f2bfbits(Wg_u[k * 64 + n]);
        }
        {
            int idx = gid;                              // 4096 elements, 1 iter
            int r = idx >> 6, k = idx & 63;
            tePi[idx] = (r < L) ? (unsigned short)f2bfbits(te_i[r * 64 + k]) : 0;
            tePu[idx] = (r < L) ? (unsigned short)f2bfbits(te_u[r * 64 + k]) : 0;
            int d = idx >> 6, rr = idx & 63;
            tkPi[idx] = (rr < L) ? (unsigned short)f2bfbits(tk_i[rr * 64 + d]) : 0;
            tkPu[idx] = (rr < L) ? (unsigned short)f2bfbits(tk_u[rr * 64 + d]) : 0;
        }
    }
}

// ---------------- K2: fused attention, both sides, MFMA math ----------------
__global__ __launch_bounds__(256, 5) void attn_fused(
    const unsigned int* __restrict__ H,
    const float* __restrict__ user_feat, const float* __restrict__ item_feat,
    const unsigned short* __restrict__ WgPi, const unsigned short* __restrict__ WgPu,
    const unsigned short* __restrict__ tePi, const unsigned short* __restrict__ tePu,
    const unsigned short* __restrict__ tkPi, const unsigned short* __restrict__ tkPu,
    const int* __restrict__ item_nbr, const int* __restrict__ item_time,
    const int* __restrict__ user_nbr, const int* __restrict__ user_time,
    float* __restrict__ out)
{
    __shared__ unsigned int lds[4 * PW];   // 31616 B -> 5 blocks/CU

    const int tid = threadIdx.x, lane = tid & 63, wid = tid >> 6;
    const bool iside = blockIdx.x < (NUM_I / 4);
    const int bb = iside ? blockIdx.x : blockIdx.x - NUM_I / 4;
    const int n = bb * 4 + wid;
    const int src_base = iside ? 0 : NUM_U;
    const int dst_base = iside ? NUM_U : 0;
    const float* dst_feat = iside ? item_feat : user_feat;
    const unsigned short* WgP  = iside ? WgPi : WgPu;
    const unsigned short* teP  = iside ? tePi : tePu;
    const unsigned short* tekP = iside ? tkPi : tkPu;
    const int* nbr   = iside ? item_nbr  : user_nbr;
    const int* timev = iside ? item_time : user_time;
    float* outp = out + (iside ? (size_t)NUM_U * D : 0);

    const int q4 = lane >> 4, c16 = lane & 15;

    // per-wave LDS slices (all 16B-aligned at their bases)
    unsigned int*   wld    = lds + wid * PW;
    unsigned int*   mbw    = wld;                            // rows 0..50, stride 33 dw
    unsigned short* mbw_sh = (unsigned short*)mbw;
    float*          escf   = (float*)(wld + 1684);           // e|e1|teh (192 f32)
    unsigned short* cat    = (unsigned short*)(wld + 1684);  // overlay: [hl|hs] bf16
    unsigned short* dla    = (unsigned short*)(wld + 1876);  // dh|lm, overlay alpha|a1|beta

    // zero pad row 50 (k-clamp target for sums MFMA)
    if (lane < 33) mbw[1650 + lane] = 0;

    // ---- metadata ----
    int t   = (lane < L) ? timev[(size_t)n * L + lane] : 0;
    int nbv = (lane < L) ? nbr[(size_t)n * L + lane]  : 0;
    unsigned int key  = (lane < L) ? ((((unsigned)t) << 6) | (unsigned)lane) : 0u;
    unsigned int key2 = (lane < L) ? ((((unsigned)t) << 6) | (unsigned)(63 - lane)) : 0u;

    int rank = 0;
#pragma unroll
    for (int j = 0; j < L; j++) {
        unsigned int kj = (unsigned int)rli((int)key, j);
        rank += (kj < key) ? 1 : 0;
    }
    int re_o = (lane < L) ? (L - 1 - rank) : lane;   // pad lanes: distinct slots

    unsigned int m2 = key2;
#pragma unroll
    for (int s = 32; s; s >>= 1) { unsigned int o2 = __shfl_xor(m2, s); m2 = (o2 > m2) ? o2 : m2; }
    const int last = 63 - (int)(m2 & 63u);

    // ---- dh from packed H ----
    unsigned int ud = H[(size_t)(dst_base + n) * 32 + (lane >> 1)];
    float dh = (lane & 1) ? hif(ud) : lof(ud);
    dla[lane] = (unsigned short)f2bfbits(dh);

    // ---- gather mailbox rows (2 rows/iter, half-wave each) ----
    {
        const unsigned int* Hs = H + (size_t)src_base * 32;
        int half = lane >> 5, col = lane & 31;
#pragma unroll
        for (int l = 0; l < L; l += 2) {
            int ra = rli(nbv, l), rb = rli(nbv, l + 1);
            int r = half ? rb : ra;
            mbw[(l + half) * 33 + col] = Hs[(size_t)r * 32 + col];
        }
    }
    // same-wave LDS write->read ordering via lgkmcnt; no barrier.

    unsigned int ulm = mbw[last * 33 + (lane >> 1)];
    float lm = (lane & 1) ? hif(ulm) : lof(ulm);
    dla[64 + lane] = (unsigned short)f2bfbits(lm);

    // ---- scores + teh via MFMA: D=[dh;lm]·M^T, D_t=[dh]·te^T ----
    f32x4 zero4 = {0.f, 0.f, 0.f, 0.f};
    f32x4 acc_e[4], acc_t[4];
#pragma unroll
    for (int nt = 0; nt < 4; nt++) { acc_e[nt] = zero4; acc_t[nt] = zero4; }
#pragma unroll
    for (int kt = 0; kt < 2; kt++) {
        short8x afr = *(const short8x*)(dla + (c16 & 1) * 64 + kt * 32 + q4 * 8);
#pragma unroll
        for (int nt = 0; nt < 4; nt++) {
            int row = c16 + 16 * nt;
            int rowc = (row > 50) ? 50 : row;       // rows >50 masked later; keep in-bounds
            union { short8x v; unsigned int u[4]; } bu;
            int base = rowc * 33 + kt * 16 + q4 * 4;
            bu.u[0] = mbw[base + 0]; bu.u[1] = mbw[base + 1];
            bu.u[2] = mbw[base + 2]; bu.u[3] = mbw[base + 3];
            acc_e[nt] = __builtin_amdgcn_mfma_f32_16x16x32_bf16(afr, bu.v, acc_e[nt], 0, 0, 0);
            short8x bt = *(const short8x*)(teP + row * 64 + kt * 32 + q4 * 8);
            acc_t[nt] = __builtin_amdgcn_mfma_f32_16x16x32_bf16(afr, bt, acc_t[nt], 0, 0, 0);
        }
    }
    if (q4 == 0) {
#pragma unroll
        for (int nt = 0; nt < 4; nt++) {
            escf[c16 + 16 * nt]       = acc_e[nt][0];   // e
            escf[64 + c16 + 16 * nt]  = acc_e[nt][1];   // e1
            escf[128 + c16 + 16 * nt] = acc_t[nt][0];   // teh (rank-indexed)
        }
    }
    float e  = escf[lane];
    float e1 = escf[64 + lane];
    float th = escf[128 + re_o];

    e = (e + th) * 0.125f;
    e1 *= 0.125f;
    if (lane >= L) { e = -3e38f; e1 = -3e38f; }

    // ---- dual softmax over neighbors ----
    float mx = e;
#pragma unroll
    for (int s = 32; s; s >>= 1) { float o2 = __shfl_xor(mx, s); mx = (o2 > mx) ? o2 : mx; }
    float ex = __expf(e - mx);
    float sm = ex;
#pragma unroll
    for (int s = 32; s; s >>= 1) sm += __shfl_xor(sm, s);
    float alpha = ex / sm;

    float mx1 = e1;
#pragma unroll
    for (int s = 32; s; s >>= 1) { float o2 = __shfl_xor(mx1, s); mx1 = (o2 > mx1) ? o2 : mx1; }
    float ex1 = __expf(e1 - mx1);
    float sm1 = ex1;
#pragma unroll
    for (int s = 32; s; s >>= 1) sm1 += __shfl_xor(sm1, s);
    float aw = ex1 / sm1;

    // ---- alpha/a1/beta (bf16) overlay onto dla (dh/lm dead after scores) ----
    dla[lane]       = (unsigned short)f2bfbits(alpha);
    dla[64 + lane]  = (unsigned short)f2bfbits(aw);
    dla[128 + re_o] = (unsigned short)f2bfbits(alpha);   // beta[r]: alpha at rank r

    // ---- sums via MFMA: [alpha;a1]·M (col-reads) + [beta]·tek^T ----
    f32x4 acc_s[4], acc_k[4];
#pragma unroll
    for (int nt = 0; nt < 4; nt++) { acc_s[nt] = zero4; acc_k[nt] = zero4; }
#pragma unroll
    for (int kt = 0; kt < 2; kt++) {
        short8x aS = *(const short8x*)(dla + (c16 & 1) * 64 + kt * 32 + q4 * 8);
        short8x aB = *(const short8x*)(dla + 128 + kt * 32 + q4 * 8);
#pragma unroll
        for (int nt = 0; nt < 4; nt++) {
            int dcol = c16 + 16 * nt;
            short8x bM;
            if (kt == 0) {
                int b0 = (q4 * 8) * 66 + dcol;
#pragma unroll
                for (int i = 0; i < 8; i++) bM[i] = (short)mbw_sh[b0 + i * 66];
            } else {
#pragma unroll
                for (int i = 0; i < 8; i++) {
                    int k = 32 + q4 * 8 + i;
                    int kk = (k < L) ? k : 50;           // row 50 zeroed
                    bM[i] = (short)mbw_sh[kk * 66 + dcol];
                }
            }
            acc_s[nt] = __builtin_amdgcn_mfma_f32_16x16x32_bf16(aS, bM, acc_s[nt], 0, 0, 0);
            short8x bK = *(const short8x*)(tekP + dcol * 64 + kt * 32 + q4 * 8);
            acc_k[nt] = __builtin_amdgcn_mfma_f32_16x16x32_bf16(aB, bK, acc_k[nt], 0, 0, 0);
        }
    }
    // cat = [hl|hs] overlay onto escf (dead after softmax)
    if (q4 == 0) {
#pragma unroll
        for (int nt = 0; nt < 4; nt++) {
            cat[c16 + 16 * nt]      = (unsigned short)f2bfbits(acc_s[nt][0] + acc_k[nt][0]);
            cat[64 + c16 + 16 * nt] = (unsigned short)f2bfbits(acc_s[nt][1]);
        }
    }
    __syncthreads();   // only barrier: epilogue mixes waves' cat rows

    // ---- epilogue: out = elu(cat @ Wg + f) ----
    short8x bfr[4];
#pragma unroll
    for (int tK = 0; tK < 4; tK++)
        bfr[tK] = *(const short8x*)(WgP + (wid * 16 + c16) * 128 + tK * 32 + q4 * 8);

    const unsigned short* catw = (const unsigned short*)(lds + (lane & 3) * PW + 1684);
    f32x4 acc = zero4;
#pragma unroll
    for (int tK = 0; tK < 4; tK++) {
        short8x a = *(const short8x*)(catw + tK * 32 + q4 * 8);
        acc = __builtin_amdgcn_mfma_f32_16x16x32_bf16(a, bfr[tK], acc, 0, 0, 0);
    }
    float r01 = (q4 & 1) ? acc[1] : acc[0];
    float r23 = (q4 & 1) ? acc[3] : acc[2];
    float pv  = (q4 & 2) ? r23 : r01;

    int node = bb * 4 + q4;
    float fres = dst_feat[(size_t)node * D + wid * 16 + c16];
    float oo = pv + fres;
    oo = (oo > 0.f) ? oo : (__expf(oo) - 1.f);
    outp[(size_t)node * D + wid * 16 + c16] = oo;
}

// ---------------- fallback: round-5 monolith (passed, 447us) ---------------
__global__ __launch_bounds__(256) void attn_mono(
    const float* __restrict__ src_feat, const float* __restrict__ dst_feat,
    const float* __restrict__ W_src, const float* __restrict__ W_dst,
    const float* __restrict__ Wg, const float* __restrict__ te,
    const float* __restrict__ tek, const int* __restrict__ nbr,
    const int* __restrict__ timev, float* __restrict__ out)
{
    __shared__ unsigned int ws32[64 * 33];
    __shared__ unsigned int te32[L * 33];
    __shared__ unsigned int mbs[4][L * 33];
    const int tid = threadIdx.x, lane = tid & 63, wid = tid >> 6;
    const int n = blockIdx.x * 4 + wid;
    {
        const float2* Wf2 = (const float2*)W_src;
        const float2* Te2 = (const float2*)te;
        for (int idx = tid; idx < 2048; idx += 256) {
            float2 w = Wf2[idx];
            ws32[(idx >> 5) * 33 + (idx & 31)] = packbf(w.x, w.y);
            if (idx < 1600) {
                float2 t2 = Te2[idx];
                te32[(idx >> 5) * 33 + (idx & 31)] = packbf(t2.x, t2.y);
            }
        }
    }
    __syncthreads();
    int t  = (lane < L) ? timev[(size_t)n * L + lane] : 0;
    int nb = (lane < L) ? nbr[(size_t)n * L + lane]  : 0;
    unsigned int key  = (lane < L) ? ((((unsigned)t) << 6) | (unsigned)lane) : 0u;
    unsigned int key2 = (lane < L) ? ((((unsigned)t) << 6) | (unsigned)(63 - lane)) : 0u;
    int rank = 0;
#pragma unroll
    for (int j = 0; j < L; j++) {
        unsigned int kj = (unsigned int)rli((int)key, j);
        rank += (kj < key) ? 1 : 0;
    }
    int re_o = (lane < L) ? (L - 1 - rank) : 0;
    unsigned int m2 = key2;
#pragma unroll
    for (int s = 32; s; s >>= 1) { unsigned int o2 = __shfl_xor(m2, s); m2 = (o2 > m2) ? o2 : m2; }
    const int last = 63 - (int)(m2 & 63u);
    const int rr = (lane < L) ? lane : (L - 1);
    float f = dst_feat[(size_t)n * D + lane];
    float dh;
    {
        float b0 = 0.f, b1 = 0.f, b2 = 0.f, b3 = 0.f;
#pragma unroll
        for (int k = 0; k < 64; k += 4) {
            b0 += rl(f, k + 0) * W_dst[(k + 0) * 64 + lane];
            b1 += rl(f, k + 1) * W_dst[(k + 1) * 64 + lane];
            b2 += rl(f, k + 2) * W_dst[(k + 2) * 64 + lane];
            b3 += rl(f, k + 3) * W_dst[(k + 3) * 64 + lane];
        }
        dh = (b0 + b1) + (b2 + b3);
    }
    float v1;
    {
        float b0 = 0.f, b1 = 0.f, b2 = 0.f, b3 = 0.f;
#pragma unroll
        for (int j = 0; j < 32; j += 2) {
            unsigned int u0 = ws32[lane * 33 + j];
            unsigned int u1 = ws32[lane * 33 + j + 1];
            b0 += lof(u0) * rl(dh, 2 * j + 0);
            b1 += hif(u0) * rl(dh, 2 * j + 1);
            b2 += lof(u1) * rl(dh, 2 * j + 2);
            b3 += hif(u1) * rl(dh, 2 * j + 3);
        }
        v1 = (b0 + b1) + (b2 + b3);
    }
    unsigned int* mbw = mbs[wid];
    {
        const float2* src2 = (const float2*)src_feat;
        int half = lane >> 5, col = lane & 31;
#pragma unroll
        for (int l = 0; l < L; l += 2) {
            int ra = rli(nb, l), rb = rli(nb, l + 1);
            int r = half ? rb : ra;
            float2 v = src2[(size_t)r * 32 + col];
            mbw[(l + half) * 33 + col] = packbf(v.x, v.y);
        }
    }
    __syncthreads();
    unsigned int ul = mbw[last * 33 + (lane >> 1)];
    float rlast = (lane & 1) ? hif(ul) : lof(ul);
    float g;
    {
        float b0 = 0.f, b1 = 0.f, b2 = 0.f, b3 = 0.f;
#pragma unroll
        for (int k = 0; k < 64; k += 4) {
            b0 += rl(rlast, k + 0) * W_src[(k + 0) * 64 + lane];
            b1 += rl(rlast, k + 1) * W_src[(k + 1) * 64 + lane];
            b2 += rl(rlast, k + 2) * W_src[(k + 2) * 64 + lane];
            b3 += rl(rlast, k + 3) * W_src[(k + 3) * 64 + lane];
        }
        g = (b0 + b1) + (b2 + b3);
    }
    float v2;
    {
        float b0 = 0.f, b1 = 0.f, b2 = 0.f, b3 = 0.f;
#pragma unroll
        for (int j = 0; j < 32; j += 2) {
            unsigned int u0 = ws32[lane * 33 + j];
            unsigned int u1 = ws32[lane * 33 + j + 1];
            b0 += lof(u0) * rl(g, 2 * j + 0);
            b1 += hif(u0) * rl(g, 2 * j + 1);
            b2 += lof(u1) * rl(g, 2 * j + 2);
            b3 += hif(u1) * rl(g, 2 * j + 3);
        }
        v2 = (b0 + b1) + (b2 + b3);
    }
    float teh;
    {
        float b0 = 0.f, b1 = 0.f, b2 = 0.f, b3 = 0.f;
#pragma unroll
        for (int j = 0; j < 32; j += 2) {
            unsigned int u0 = te32[rr * 33 + j];
            unsigned int u1 = te32[rr * 33 + j + 1];
            b0 += lof(u0) * rl(dh, 2 * j + 0);
            b1 += hif(u0) * rl(dh, 2 * j + 1);
            b2 += lof(u1) * rl(dh, 2 * j + 2);
            b3 += hif(u1) * rl(dh, 2 * j + 3);
        }
        teh = (b0 + b1) + (b2 + b3);
    }
    float e, e1;
    {
        float ea = 0.f, eb = 0.f, qa = 0.f, qb = 0.f;
#pragma unroll
        for (int j = 0; j < 32; j += 2) {
            unsigned int u0 = mbw[rr * 33 + j];
            unsigned int u1 = mbw[rr * 33 + j + 1];
            float m0 = lof(u0), m1 = hif(u0), m2f = lof(u1), m3 = hif(u1);
            ea += m0 * rl(v1, 2 * j + 0) + m1 * rl(v1, 2 * j + 1);
            eb += m2f * rl(v1, 2 * j + 2) + m3 * rl(v1, 2 * j + 3);
            qa += m0 * rl(v2, 2 * j + 0) + m1 * rl(v2, 2 * j + 1);
            qb += m2f * rl(v2, 2 * j + 2) + m3 * rl(v2, 2 * j + 3);
        }
        e = ea + eb; e1 = qa + qb;
    }
    e = (e + __shfl(teh, re_o)) * 0.125f;
    e1 *= 0.125f;
    if (lane >= L) { e = -3e38f; e1 = -3e38f; }
    float mx = e;
#pragma unroll
    for (int s = 32; s; s >>= 1) { float o2 = __shfl_xor(mx, s); mx = (o2 > mx) ? o2 : mx; }
    float ex = __expf(e - mx);
    float sm = ex;
#pragma unroll
    for (int s = 32; s; s >>= 1) sm += __shfl_xor(sm, s);
    float alpha = ex / sm;
    float mx1 = e1;
#pragma unroll
    for (int s = 32; s; s >>= 1) { float o2 = __shfl_xor(mx1, s); mx1 = (o2 > mx1) ? o2 : mx1; }
    float ex1 = __expf(e1 - mx1);
    float sm1 = ex1;
#pragma unroll
    for (int s = 32; s; s >>= 1) sm1 += __shfl_xor(sm1, s);
    float aw = ex1 / sm1;
    float sl, ss, tacc;
    {
        float sA = 0.f, sB = 0.f, hA = 0.f, hB = 0.f, tA = 0.f, tB = 0.f;
        int hcol = lane >> 1, odd = lane & 1;
#pragma unroll
        for (int l = 0; l < L; l += 2) {
            float saA = rl(alpha, l),     s1A = rl(aw, l);
            float saB = rl(alpha, l + 1), s1B = rl(aw, l + 1);
            int   roA = rli(re_o, l),     roB = rli(re_o, l + 1);
            unsigned int uA = mbw[(l + 0) * 33 + hcol];
            unsigned int uB = mbw[(l + 1) * 33 + hcol];
            float mA = odd ? hif(uA) : lof(uA);
            float mB = odd ? hif(uB) : lof(uB);
            sA += saA * mA; hA += s1A * mA; tA += saA * tek[roA * 64 + lane];
            sB += saB * mB; hB += s1B * mB; tB += saB * tek[roB * 64 + lane];
        }
        sl = sA + sB; ss = hA + hB; tacc = tA + tB;
    }
    float hl, hs;
    {
        float lA = 0.f, lB = 0.f, sA = 0.f, sB = 0.f;
#pragma unroll
        for (int k = 0; k < 64; k += 2) {
            float w0 = W_src[(k + 0) * 64 + lane];
            float w1 = W_src[(k + 1) * 64 + lane];
            lA += rl(sl, k + 0) * w0; sA += rl(ss, k + 0) * w0;
            lB += rl(sl, k + 1) * w1; sB += rl(ss, k + 1) * w1;
        }
        hl = tacc + lA + lB; hs = sA + sB;
    }
    float o;
    {
        float o0 = 0.f, o1 = 0.f, o2 = 0.f, o3 = 0.f;
#pragma unroll
        for (int k = 0; k < 64; k += 2) {
            o0 += rl(hl, k + 0) * Wg[(k + 0) * 64 + lane];
            o1 += rl(hl, k + 1) * Wg[(k + 1) * 64 + lane];
            o2 += rl(hs, k + 0) * Wg[(k + 64) * 64 + lane];
            o3 += rl(hs, k + 1) * Wg[(k + 65) * 64 + lane];
        }
        o = f + (o0 + o1) + (o2 + o3);
    }
    o = (o > 0.f) ? o : (__expf(o) - 1.f);
    out[(size_t)n * D + lane] = o;
}

extern "C" void kernel_launch(void* const* d_in, const int* in_sizes, int n_in,
                              void* d_out, int out_size, void* d_ws, size_t ws_size,
                              hipStream_t stream) {
    const float* user_feat = (const float*)d_in[0];
    const float* item_feat = (const float*)d_in[1];
    const float* W_u  = (const float*)d_in[2];
    const float* W_i  = (const float*)d_in[3];
    const float* Wg_u = (const float*)d_in[4];
    const float* Wg_i = (const float*)d_in[5];
    const float* i_te   = (const float*)d_in[6];
    const float* i_te_k = (const float*)d_in[7];
    const float* u_te   = (const float*)d_in[8];
    const float* u_te_k = (const float*)d_in[9];
    const int* item_nbr  = (const int*)d_in[10];
    const int* item_time = (const int*)d_in[11];
    const int* user_nbr  = (const int*)d_in[12];
    const int* user_time = (const int*)d_in[13];
    (void)in_sizes; (void)n_in; (void)out_size;

    float* outp = (float*)d_out;
    const size_t H_BYTES = (size_t)(NUM_U + NUM_I) * 32 * 4;            // 6.4 MB
    const size_t NEED = H_BYTES + 2 * 16384 + 4 * 8192;                 // +64 KB aux

    if (ws_size >= NEED) {
        unsigned int* Hp = (unsigned int*)d_ws;
        unsigned char* aux = (unsigned char*)d_ws + H_BYTES;
        unsigned short* WgPi = (unsigned short*)(aux);
        unsigned short* WgPu = (unsigned short*)(aux + 16384);
        unsigned short* tePi = (unsigned short*)(aux + 32768);
        unsigned short* tePu = (unsigned short*)(aux + 40960);
        unsigned short* tkPi = (unsigned short*)(aux + 49152);
        unsigned short* tkPu = (unsigned short*)(aux + 57344);

        prep<<<3141, 256, 0, stream>>>(user_feat, item_feat, W_u, W_i,
                                       Wg_i, Wg_u, i_te, u_te, i_te_k, u_te_k,
                                       Hp, WgPi, WgPu, tePi, tePu, tkPi, tkPu);
        attn_fused<<<(NUM_I + NUM_U) / 4, 256, 0, stream>>>(
            Hp, user_feat, item_feat, WgPi, WgPu, tePi, tePu, tkPi, tkPu,
            item_nbr, item_time, user_nbr, user_time, outp);
    } else {
        attn_mono<<<NUM_I / 4, 256, 0, stream>>>(
            user_feat, item_feat, W_u, W_i, Wg_i, i_te, i_te_k,
            item_nbr, item_time, outp + (size_t)NUM_U * D);
        attn_mono<<<NUM_U / 4, 256, 0, stream>>>(
            item_feat, user_feat, W_i, W_u, Wg_u, u_te, u_te_k,
            user_nbr, user_time, outp);
    }
}